// Round 2
// baseline (2713.833 us; speedup 1.0000x reference)
//
#include <hip/hip_runtime.h>
#include <hip/hip_bf16.h>

// Problem constants
#define DD 2048
#define TT 512
#define NBLK 64           // recurrence workgroups (plus NBLK y-consumer workgroups)
#define HF_SLOT 32768     // elements per h fragment slot (16 x 2048)
#define KT 64             // K tiles of 32 (DD/32)
#define FSTRIDE 16        // dwords between flags (64 B -> one LLC line each)
#define SENT32 0x7FC07FC0u   // two bf16 NaNs; tanh/h0 never produce NaN bf16

typedef __attribute__((ext_vector_type(4))) float  f32x4;
typedef __attribute__((ext_vector_type(8))) short  bf16x8;
typedef __attribute__((ext_vector_type(8))) unsigned short u16x8;
typedef unsigned short ushort_t;
typedef unsigned long long u64_t;

__device__ __forceinline__ void gld_lds16(const void* g, void* l) {
    __builtin_amdgcn_global_load_lds(
        (const __attribute__((address_space(1))) unsigned int*)g,
        (__attribute__((address_space(3))) unsigned int*)l, 16, 0, 0);
}

__device__ __forceinline__ ushort_t f2bf(float v) {
    __hip_bfloat16 h = __float2bfloat16(v);
    return *(ushort_t*)&h;
}

// LLC-coherent (agent-scope, relaxed) accessors — no wbl2/inv emitted.
__device__ __forceinline__ u64_t llc_load64(const u64_t* p) {
    return __hip_atomic_load(p, __ATOMIC_RELAXED, __HIP_MEMORY_SCOPE_AGENT);
}
__device__ __forceinline__ void llc_store64(u64_t* p, u64_t v) {
    __hip_atomic_store(p, v, __ATOMIC_RELAXED, __HIP_MEMORY_SCOPE_AGENT);
}
__device__ __forceinline__ unsigned llc_load32(const unsigned* p) {
    return __hip_atomic_load(p, __ATOMIC_RELAXED, __HIP_MEMORY_SCOPE_AGENT);
}
__device__ __forceinline__ float llc_loadf(const float* p) {
    return __hip_atomic_load(p, __ATOMIC_RELAXED, __HIP_MEMORY_SCOPE_AGENT);
}

// ---------------------------------------------------------------------------
// Convert fp32 row-major [mtiles*16][2048] -> bf16 A-fragment layout
// ---------------------------------------------------------------------------
__global__ void conv_frag(const float* __restrict__ src, ushort_t* __restrict__ dst) {
    int id = blockIdx.x * 256 + threadIdx.x;     // one thread per 8 elements
    int l  = id & 63;
    int sk = (id >> 6) & 63;
    int mt = id >> 12;
    const float* s = src + (size_t)(mt * 16 + (l & 15)) * DD + sk * 32 + ((l >> 4) * 8);
    float4 a = *(const float4*)s;
    float4 b = *(const float4*)(s + 4);
    u16x8 r;
    r[0] = f2bf(a.x); r[1] = f2bf(a.y); r[2] = f2bf(a.z); r[3] = f2bf(a.w);
    r[4] = f2bf(b.x); r[5] = f2bf(b.y); r[6] = f2bf(b.z); r[7] = f2bf(b.w);
    *(u16x8*)(dst + (size_t)id * 8) = r;
}

// ---------------------------------------------------------------------------
// Transpose fp32 W[k][n] -> bf16 Wt[n][k]
// ---------------------------------------------------------------------------
__global__ void conv_wt(const float* __restrict__ W, ushort_t* __restrict__ Wt) {
    int id = blockIdx.x * 256 + threadIdx.x;
    int n  = id & (DD - 1);
    int k8 = id >> 11;
    u16x8 r;
#pragma unroll
    for (int j = 0; j < 8; ++j)
        r[j] = f2bf(W[(size_t)(k8 * 8 + j) * DD + n]);
    *(u16x8*)(Wt + (size_t)n * DD + k8 * 8) = r;
}

// ---------------------------------------------------------------------------
// Fill Hf slots 1..512 with the bf16-NaN sentinel (runs after gemm_frag,
// since the X fragments alias this region during phase 1).
// ---------------------------------------------------------------------------
__global__ void fill_sent(u64_t* __restrict__ dst) {
    size_t id = (size_t)blockIdx.x * 256 + threadIdx.x;   // 16 B per thread
    u64_t v = 0x7FC07FC07FC07FC0ull;
    dst[id * 2]     = v;
    dst[id * 2 + 1] = v;
}

// ---------------------------------------------------------------------------
// m97-style GEMM: C[M x 2048] = Af @ Bt^T  (phase 1 only)
// ---------------------------------------------------------------------------
__global__ __launch_bounds__(256) void gemm_frag(
    const ushort_t* __restrict__ Af, const ushort_t* __restrict__ Bt,
    float* __restrict__ C) {
    __shared__ ushort_t lA[8 * 64 * 8];
    __shared__ ushort_t lB[8 * 64 * 8];
    int tid = threadIdx.x;
    int w = tid >> 6, l = tid & 63;
    int wm = w >> 1, wn = w & 1;
    int quad = l >> 4, col = l & 15;
    int mt0 = blockIdx.x * 8;
    int n0  = blockIdx.y * 128;

    f32x4 acc[4][4] = {};

    for (int sk = 0; sk < KT; ++sk) {
        __syncthreads();
#pragma unroll
        for (int q = 0; q < 2; ++q) {
            int i = w * 2 + q;
            const ushort_t* ga = Af + ((size_t)((mt0 + i) * 64 + sk) * 64 + l) * 8;
            gld_lds16(ga, &lA[i * 512]);
            int jt = i;
            const ushort_t* gb = Bt + (size_t)(n0 + jt * 16 + col) * DD + sk * 32 + quad * 8;
            gld_lds16(gb, &lB[jt * 512]);
        }
        __syncthreads();
        bf16x8 af[4], bf[4];
#pragma unroll
        for (int i = 0; i < 4; ++i) af[i] = *(const bf16x8*)&lA[((wm * 4 + i) * 64 + l) * 8];
#pragma unroll
        for (int j = 0; j < 4; ++j) bf[j] = *(const bf16x8*)&lB[((wn * 4 + j) * 64 + l) * 8];
#pragma unroll
        for (int i = 0; i < 4; ++i)
#pragma unroll
            for (int j = 0; j < 4; ++j)
                acc[i][j] = __builtin_amdgcn_mfma_f32_16x16x32_bf16(af[i], bf[j], acc[i][j], 0, 0, 0);
    }

#pragma unroll
    for (int i = 0; i < 4; ++i)
#pragma unroll
        for (int j = 0; j < 4; ++j) {
            int rg0 = (mt0 + wm * 4 + i) * 16 + quad * 4;
            int cg  = n0 + (wn * 4 + j) * 16 + col;
#pragma unroll
            for (int r = 0; r < 4; ++r)
                C[(size_t)(rg0 + r) * DD + cg] = acc[i][j][r];
        }
}

// ---------------------------------------------------------------------------
// Fused recurrence + y-GEMM consumers. 128 blocks x 256 threads.
//   blocks 0..63   : recurrence, column slice 32*b (= k-slice b of h)
//   blocks 64..127 : y = h_t @ Wo slice, write ys fp32
// Sync protocol (flag-as-hint + sentinel-verify):
//   - producer stores h slice + flag fire-and-forget (NO store-ack waitcnt)
//   - consumer wave w polls only its 16 producer flags (blocks w*16..w*16+15),
//     then loads its 16 slices and verifies per-u32 against the bf16-NaN
//     sentinel; rare stragglers are re-loaded. Each u32 comes from one 8 B
//     store, so a u32 != SENT32 check is all-new-or-all-old.
//   - waves 0/1 own disjoint halves of the output fragment (u64s 0..63 /
//     64..127), so each publishes its half directly after a same-wave
//     hstage round trip — no barrier on the publish path.
// ---------------------------------------------------------------------------
__global__ __launch_bounds__(256, 1) void rnn_fused(
    const ushort_t* __restrict__ Wht,   // bf16 [n][k]
    const ushort_t* __restrict__ Wot,   // bf16 [n][k]
    ushort_t* __restrict__ Hf,          // (TT+1) slots of A-fragment h
    const float* __restrict__ A32,      // fp32 [TT*16][2048] = x@Wx (aliases ys!)
    float* __restrict__ out,            // [0:HF_SLOT) h_final, then ys
    unsigned* __restrict__ flags) {     // NBLK flags, 64B stride, zeroed
    __shared__ ushort_t lW[4 * 16 * 2 * 512];   // 128 KB (Wh or Wo slice)
    __shared__ float scr[2048];                 // 8 KB reduction scratch
    __shared__ ushort_t hstage[512];            // 1 KB h-output staging (rnn only)
    int tid = threadIdx.x;
    int w = tid >> 6, l = tid & 63;
    int quad = l >> 4, col = l & 15;
    bool is_rnn = blockIdx.x < NBLK;
    int b = is_rnn ? blockIdx.x : blockIdx.x - NBLK;
    int c0 = b * 32;
    float* ys = out + HF_SLOT;

    // Stage this block's weight slice (2048 K x 32 N) into LDS.
    const ushort_t* Wsrc = is_rnn ? Wht : Wot;
#pragma unroll
    for (int s = 0; s < 16; ++s) {
        int sk = w * 16 + s;
#pragma unroll
        for (int jt = 0; jt < 2; ++jt) {
            const ushort_t* gb = Wsrc + (size_t)(c0 + jt * 16 + col) * DD + sk * 32 + quad * 8;
            gld_lds16(gb, &lW[((sk * 2 + jt) << 9)]);
        }
    }
    __syncthreads();

    // Each wave polls only the flags of the 16 producer blocks whose slices
    // it consumes (slice sk = producer block sk; wave w owns sk=w*16..+15).
    const unsigned* fp = &flags[(w * 16 + (l & 15)) * FSTRIDE];

    for (int t = 1; t <= TT; ++t) {
        // rnn: prefetch A32 addend before the poll (latency hidden by wait).
        float av[4];
        if (is_rnn && w < 2) {
#pragma unroll
            for (int r = 0; r < 4; ++r)
                av[r] = llc_loadf(&A32[(size_t)((t - 1) * 16 + quad * 4 + r) * DD + c0 + w * 16 + col]);
        }

        // Per-wave poll (no barrier): rnn needs h_{t-1}, y needs h_t.
        unsigned tgt = is_rnn ? (unsigned)(t - 1) : (unsigned)t;
        {
            unsigned f;
            do { f = llc_load32(fp); } while (!__all((int)(f >= tgt)));
        }

        // Load h fragments from LLC; verify sentinel; retry rare stragglers.
        const ushort_t* hsrc = Hf + (size_t)(is_rnn ? t - 1 : t) * HF_SLOT;
        const u64_t* hq = (const u64_t*)hsrc + ((size_t)(w * 16) * 64 + l) * 2;

        f32x4 aA0 = {0.f,0.f,0.f,0.f}, aA1 = {0.f,0.f,0.f,0.f};
        f32x4 aB0 = {0.f,0.f,0.f,0.f}, aB1 = {0.f,0.f,0.f,0.f};
        unsigned pend = 0xFFFFu;   // wave-uniform: cleared only via __all
        u64_t q0[16], q1[16];
        while (pend) {
#pragma unroll
            for (int s = 0; s < 16; ++s)
                if (pend & (1u << s)) {
                    const u64_t* p = hq + (size_t)s * 128;
                    q0[s] = llc_load64(p);
                    q1[s] = llc_load64(p + 1);
                }
#pragma unroll
            for (int s = 0; s < 16; ++s)
                if (pend & (1u << s)) {
                    unsigned x0 = (unsigned)q0[s], x1 = (unsigned)(q0[s] >> 32);
                    unsigned x2 = (unsigned)q1[s], x3 = (unsigned)(q1[s] >> 32);
                    bool ok = (x0 != SENT32) & (x1 != SENT32) & (x2 != SENT32) & (x3 != SENT32);
                    if (__all((int)ok)) {
                        pend &= ~(1u << s);
                        union { u64_t q[2]; bf16x8 v; } u;
                        u.q[0] = q0[s]; u.q[1] = q1[s];
                        int sk = w * 16 + s;
                        bf16x8 w0 = *(const bf16x8*)&lW[((sk * 2 + 0) << 9) + l * 8];
                        bf16x8 w1 = *(const bf16x8*)&lW[((sk * 2 + 1) << 9) + l * 8];
                        if (s < 8) {
                            aA0 = __builtin_amdgcn_mfma_f32_16x16x32_bf16(u.v, w0, aA0, 0, 0, 0);
                            aA1 = __builtin_amdgcn_mfma_f32_16x16x32_bf16(u.v, w1, aA1, 0, 0, 0);
                        } else {
                            aB0 = __builtin_amdgcn_mfma_f32_16x16x32_bf16(u.v, w0, aB0, 0, 0, 0);
                            aB1 = __builtin_amdgcn_mfma_f32_16x16x32_bf16(u.v, w1, aB1, 0, 0, 0);
                        }
                    }
                }
        }
        f32x4 acc0 = aA0 + aB0;
        f32x4 acc1 = aA1 + aB1;

        *(f32x4*)&scr[((w * 2 + 0) * 64 + l) * 4] = acc0;
        *(f32x4*)&scr[((w * 2 + 1) * 64 + l) * 4] = acc1;
        __syncthreads();   // barrier A: scr ready

        if (w < 2) {   // waves 0,1 finish the 2 column tiles
            int jt = w;
            f32x4 p0 = *(f32x4*)&scr[((0 * 2 + jt) * 64 + l) * 4];
            f32x4 p1 = *(f32x4*)&scr[((1 * 2 + jt) * 64 + l) * 4];
            f32x4 p2 = *(f32x4*)&scr[((2 * 2 + jt) * 64 + l) * 4];
            f32x4 p3 = *(f32x4*)&scr[((3 * 2 + jt) * 64 + l) * 4];
            int lc = jt * 16 + col;          // 0..31 within block's column slice
            if (is_rnn) {
                int q2 = lc >> 3, jj = lc & 7;
#pragma unroll
                for (int r = 0; r < 4; ++r) {
                    int m = quad * 4 + r;    // C/D layout: row=(l>>4)*4+r
                    float x = p0[r] + p1[r] + p2[r] + p3[r] + av[r];
                    float e2 = __expf(-2.f * fabsf(x));
                    float th = copysignf((1.f - e2) / (1.f + e2), x);
                    hstage[(q2 * 16 + m) * 8 + jj] = f2bf(th);
                    if (t == TT) out[(size_t)m * DD + c0 + lc] = th;
                }
                // Same-wave hstage round trip: wave w wrote exactly u64s
                // w*64..w*64+63 (q2 in {2w,2w+1}); read back and publish own
                // half directly. Fence orders the ds_writes before the read.
                asm volatile("s_waitcnt lgkmcnt(0)" ::: "memory");
                u64_t v = ((const u64_t*)hstage)[w * 64 + l];
                u64_t* dq = (u64_t*)(Hf + (size_t)t * HF_SLOT + (size_t)b * 512);
                llc_store64(dq + w * 64 + l, v);
                // Flag is a hint (no store-ack): consumers sentinel-verify.
                if (w == 0 && l == 0)
                    __hip_atomic_store(&flags[b * FSTRIDE], (unsigned)t,
                                       __ATOMIC_RELAXED, __HIP_MEMORY_SCOPE_AGENT);
            } else {
#pragma unroll
                for (int r = 0; r < 4; ++r) {
                    int m = quad * 4 + r;
                    float y = p0[r] + p1[r] + p2[r] + p3[r];
                    ys[(size_t)((t - 1) * 16 + m) * DD + c0 + lc] = y;
                }
            }
        }

        __syncthreads();   // barrier B: protects scr/hstage reuse across t
    }
}

// ---------------------------------------------------------------------------
extern "C" void kernel_launch(void* const* d_in, const int* in_sizes, int n_in,
                              void* d_out, int out_size, void* d_ws, size_t ws_size,
                              hipStream_t stream) {
    const float* h0 = (const float*)d_in[0];
    const float* x  = (const float*)d_in[1];
    const float* Wx = (const float*)d_in[2];
    const float* Wh = (const float*)d_in[3];
    const float* Wo = (const float*)d_in[4];
    float* out = (float*)d_out;

    char* ws = (char*)d_ws;
    unsigned* flags = (unsigned*)ws;                             // 4 KB (64 flags, 64B stride)
    ushort_t* Hf  = (ushort_t*)(ws + 4096);                      // 513 slots * 64KB
    ushort_t* Xf  = Hf + HF_SLOT;                                // alias slots 1..512 (dead after phase 1)
    size_t hf_bytes = (size_t)(TT + 1) * HF_SLOT * 2;
    ushort_t* Wxt = (ushort_t*)(ws + 4096 + hf_bytes);
    ushort_t* Wht = Wxt + (size_t)DD * DD;
    ushort_t* Wot = Wht + (size_t)DD * DD;
    float* A32 = out + HF_SLOT;                                  // ys region; y writes trail A32 reads

    hipMemsetAsync(d_ws, 0, 4096, stream);

    // fp32 -> bf16 layout conversions
    conv_frag<<<8192, 256, 0, stream>>>(x, Xf);                  // X fragments
    conv_frag<<<16, 256, 0, stream>>>(h0, Hf);                   // h0 -> slot 0
    conv_wt<<<2048, 256, 0, stream>>>(Wx, Wxt);
    conv_wt<<<2048, 256, 0, stream>>>(Wh, Wht);
    conv_wt<<<2048, 256, 0, stream>>>(Wo, Wot);

    // Phase 1: A32 = X @ Wx   (fp32, lives in d_out's ys region)
    gemm_frag<<<dim3(64, 16), 256, 0, stream>>>(Xf, Wxt, A32);

    // Sentinel-fill Hf slots 1..512 (must run AFTER gemm_frag: Xf aliases them)
    fill_sent<<<8192, 256, 0, stream>>>((u64_t*)(Hf + HF_SLOT));

    // Phase 2+3 fused: recurrence + streaming y = h @ Wo
    rnn_fused<<<2 * NBLK, 256, 0, stream>>>(Wht, Wot, Hf, A32, out, flags);
}

// Round 3
// 2019.230 us; speedup vs baseline: 1.3440x; 1.3440x over previous
//
#include <hip/hip_runtime.h>
#include <hip/hip_bf16.h>

// Problem constants
#define DD 2048
#define TT 512
#define NBLK 64           // recurrence workgroups (plus NBLK y-consumer workgroups)
#define HF_SLOT 32768     // elements per h fragment slot (16 x 2048)
#define KT 64             // K tiles of 32 (DD/32)
#define FSTRIDE 16        // dwords between flag lines (64 B -> one LLC line each)

typedef __attribute__((ext_vector_type(4))) float  f32x4;
typedef __attribute__((ext_vector_type(8))) short  bf16x8;
typedef __attribute__((ext_vector_type(8))) unsigned short u16x8;
typedef unsigned short ushort_t;
typedef unsigned long long u64_t;

__device__ __forceinline__ void gld_lds16(const void* g, void* l) {
    __builtin_amdgcn_global_load_lds(
        (const __attribute__((address_space(1))) unsigned int*)g,
        (__attribute__((address_space(3))) unsigned int*)l, 16, 0, 0);
}

__device__ __forceinline__ ushort_t f2bf(float v) {
    __hip_bfloat16 h = __float2bfloat16(v);
    return *(ushort_t*)&h;
}

// LLC-coherent (agent-scope, relaxed) accessors — no wbl2/inv emitted.
__device__ __forceinline__ u64_t llc_load64(const u64_t* p) {
    return __hip_atomic_load(p, __ATOMIC_RELAXED, __HIP_MEMORY_SCOPE_AGENT);
}
__device__ __forceinline__ void llc_store64(u64_t* p, u64_t v) {
    __hip_atomic_store(p, v, __ATOMIC_RELAXED, __HIP_MEMORY_SCOPE_AGENT);
}
__device__ __forceinline__ float llc_loadf(const float* p) {
    return __hip_atomic_load(p, __ATOMIC_RELAXED, __HIP_MEMORY_SCOPE_AGENT);
}

// ---------------------------------------------------------------------------
// Convert fp32 row-major [mtiles*16][2048] -> bf16 A-fragment layout
// ---------------------------------------------------------------------------
__global__ void conv_frag(const float* __restrict__ src, ushort_t* __restrict__ dst) {
    int id = blockIdx.x * 256 + threadIdx.x;     // one thread per 8 elements
    int l  = id & 63;
    int sk = (id >> 6) & 63;
    int mt = id >> 12;
    const float* s = src + (size_t)(mt * 16 + (l & 15)) * DD + sk * 32 + ((l >> 4) * 8);
    float4 a = *(const float4*)s;
    float4 b = *(const float4*)(s + 4);
    u16x8 r;
    r[0] = f2bf(a.x); r[1] = f2bf(a.y); r[2] = f2bf(a.z); r[3] = f2bf(a.w);
    r[4] = f2bf(b.x); r[5] = f2bf(b.y); r[6] = f2bf(b.z); r[7] = f2bf(b.w);
    *(u16x8*)(dst + (size_t)id * 8) = r;
}

// ---------------------------------------------------------------------------
// Transpose fp32 W[k][n] -> bf16 Wt[n][k]
// ---------------------------------------------------------------------------
__global__ void conv_wt(const float* __restrict__ W, ushort_t* __restrict__ Wt) {
    int id = blockIdx.x * 256 + threadIdx.x;
    int n  = id & (DD - 1);
    int k8 = id >> 11;
    u16x8 r;
#pragma unroll
    for (int j = 0; j < 8; ++j)
        r[j] = f2bf(W[(size_t)(k8 * 8 + j) * DD + n]);
    *(u16x8*)(Wt + (size_t)n * DD + k8 * 8) = r;
}

// ---------------------------------------------------------------------------
// m97-style GEMM: C[M x 2048] = Af @ Bt^T  (phase 1 only)
// ---------------------------------------------------------------------------
__global__ __launch_bounds__(256) void gemm_frag(
    const ushort_t* __restrict__ Af, const ushort_t* __restrict__ Bt,
    float* __restrict__ C) {
    __shared__ ushort_t lA[8 * 64 * 8];
    __shared__ ushort_t lB[8 * 64 * 8];
    int tid = threadIdx.x;
    int w = tid >> 6, l = tid & 63;
    int wm = w >> 1, wn = w & 1;
    int quad = l >> 4, col = l & 15;
    int mt0 = blockIdx.x * 8;
    int n0  = blockIdx.y * 128;

    f32x4 acc[4][4] = {};

    for (int sk = 0; sk < KT; ++sk) {
        __syncthreads();
#pragma unroll
        for (int q = 0; q < 2; ++q) {
            int i = w * 2 + q;
            const ushort_t* ga = Af + ((size_t)((mt0 + i) * 64 + sk) * 64 + l) * 8;
            gld_lds16(ga, &lA[i * 512]);
            int jt = i;
            const ushort_t* gb = Bt + (size_t)(n0 + jt * 16 + col) * DD + sk * 32 + quad * 8;
            gld_lds16(gb, &lB[jt * 512]);
        }
        __syncthreads();
        bf16x8 af[4], bf[4];
#pragma unroll
        for (int i = 0; i < 4; ++i) af[i] = *(const bf16x8*)&lA[((wm * 4 + i) * 64 + l) * 8];
#pragma unroll
        for (int j = 0; j < 4; ++j) bf[j] = *(const bf16x8*)&lB[((wn * 4 + j) * 64 + l) * 8];
#pragma unroll
        for (int i = 0; i < 4; ++i)
#pragma unroll
            for (int j = 0; j < 4; ++j)
                acc[i][j] = __builtin_amdgcn_mfma_f32_16x16x32_bf16(af[i], bf[j], acc[i][j], 0, 0, 0);
    }

#pragma unroll
    for (int i = 0; i < 4; ++i)
#pragma unroll
        for (int j = 0; j < 4; ++j) {
            int rg0 = (mt0 + wm * 4 + i) * 16 + quad * 4;
            int cg  = n0 + (wn * 4 + j) * 16 + col;
#pragma unroll
            for (int r = 0; r < 4; ++r)
                C[(size_t)(rg0 + r) * DD + cg] = acc[i][j][r];
        }
}

// ---------------------------------------------------------------------------
// Fused recurrence + y-GEMM consumers. 128 blocks x 256 threads.
//   blocks 0..63   : recurrence, column slice 32*b, publish h_t + dual flags
//   blocks 64..127 : y = h_t @ Wo slice, consume flags, write ys fp32
// Per-step sync (round-0 protocol, publish restructured):
//   - single-wave (w==3) poll + barrier broadcast (proven fastest detect)
//   - waves 0/1 own disjoint halves of the h fragment (u64s 0..63 / 64..127
//     of hstage), so each publishes its OWN half: same-wave hstage round
//     trip (lgkmcnt(0), no barrier), 1 store/lane, vmcnt(0) ack, then its
//     own flag dword. Both flag dwords live in ONE 64 B line per block, so
//     the consumer poll is still a single 8 B load per lane.
//   This removes the pre-publish __syncthreads and halves the ack depth.
// ---------------------------------------------------------------------------
__global__ __launch_bounds__(256, 1) void rnn_fused(
    const ushort_t* __restrict__ Wht,   // bf16 [n][k]
    const ushort_t* __restrict__ Wot,   // bf16 [n][k]
    ushort_t* __restrict__ Hf,          // (TT+1) slots of A-fragment h
    const float* __restrict__ A32,      // fp32 [TT*16][2048] = x@Wx (aliases ys!)
    float* __restrict__ out,            // [0:HF_SLOT) h_final, then ys
    unsigned* __restrict__ flags) {     // NBLK lines, 64B stride; dwords 0,1 used
    __shared__ ushort_t lW[4 * 16 * 2 * 512];   // 128 KB (Wh or Wo slice)
    __shared__ float scr[2048];                 // 8 KB reduction scratch
    __shared__ ushort_t hstage[512];            // 1 KB h-output staging (rnn only)
    int tid = threadIdx.x;
    int w = tid >> 6, l = tid & 63;
    int quad = l >> 4, col = l & 15;
    bool is_rnn = blockIdx.x < NBLK;
    int b = is_rnn ? blockIdx.x : blockIdx.x - NBLK;
    int c0 = b * 32;
    float* ys = out + HF_SLOT;

    // Stage this block's weight slice (2048 K x 32 N) into LDS.
    const ushort_t* Wsrc = is_rnn ? Wht : Wot;
#pragma unroll
    for (int s = 0; s < 16; ++s) {
        int sk = w * 16 + s;
#pragma unroll
        for (int jt = 0; jt < 2; ++jt) {
            const ushort_t* gb = Wsrc + (size_t)(c0 + jt * 16 + col) * DD + sk * 32 + quad * 8;
            gld_lds16(gb, &lW[((w * 16 + s) * 2 + jt) << 9]);
        }
    }
    __syncthreads();

    for (int t = 1; t <= TT; ++t) {
        // rnn: prefetch A32 addend before the poll (latency hidden by wait).
        float av[4];
        if (is_rnn && w < 2) {
#pragma unroll
            for (int r = 0; r < 4; ++r)
                av[r] = llc_loadf(&A32[(size_t)((t - 1) * 16 + quad * 4 + r) * DD + c0 + w * 16 + col]);
        }

        // Single-wave poll, broadcast via barrier. Each lane checks BOTH
        // half-flags of one block with a single 8 B load.
        // rnn waits for h_{t-1} (>= t-1); y waits for h_t (>= t).
        unsigned tgt = is_rnn ? (unsigned)(t - 1) : (unsigned)t;
        if (w == 3) {
            u64_t f;
            do {
                f = llc_load64((const u64_t*)&flags[l * FSTRIDE]);
            } while (!__all((int)(((unsigned)f >= tgt) & ((unsigned)(f >> 32) >= tgt))));
        }
        __syncthreads();

        // Load h fragments straight from LLC.
        const ushort_t* hsrc = Hf + (size_t)(is_rnn ? t - 1 : t) * HF_SLOT;
        bf16x8 hv[16];
#pragma unroll
        for (int s = 0; s < 16; ++s) {
            int sk = w * 16 + s;
            const u64_t* p = (const u64_t*)(hsrc + (size_t)(sk * 64 + l) * 8);
            union { u64_t q[2]; bf16x8 v; } u;
            u.q[0] = llc_load64(p);
            u.q[1] = llc_load64(p + 1);
            hv[s] = u.v;
        }

        f32x4 acc0 = {0.f, 0.f, 0.f, 0.f};
        f32x4 acc1 = {0.f, 0.f, 0.f, 0.f};
#pragma unroll
        for (int s = 0; s < 16; ++s) {
            bf16x8 w0 = *(const bf16x8*)&lW[(((w * 16 + s) * 2 + 0) << 9) + l * 8];
            bf16x8 w1 = *(const bf16x8*)&lW[(((w * 16 + s) * 2 + 1) << 9) + l * 8];
            acc0 = __builtin_amdgcn_mfma_f32_16x16x32_bf16(hv[s], w0, acc0, 0, 0, 0);
            acc1 = __builtin_amdgcn_mfma_f32_16x16x32_bf16(hv[s], w1, acc1, 0, 0, 0);
        }
        *(f32x4*)&scr[((w * 2 + 0) * 64 + l) * 4] = acc0;
        *(f32x4*)&scr[((w * 2 + 1) * 64 + l) * 4] = acc1;
        __syncthreads();   // barrier A: scr ready

        if (w < 2) {   // waves 0,1 finish the 2 column tiles
            int jt = w;
            f32x4 p0 = *(f32x4*)&scr[((0 * 2 + jt) * 64 + l) * 4];
            f32x4 p1 = *(f32x4*)&scr[((1 * 2 + jt) * 64 + l) * 4];
            f32x4 p2 = *(f32x4*)&scr[((2 * 2 + jt) * 64 + l) * 4];
            f32x4 p3 = *(f32x4*)&scr[((3 * 2 + jt) * 64 + l) * 4];
            int lc = jt * 16 + col;          // 0..31 within block's column slice
            if (is_rnn) {
                int q2 = lc >> 3, jj = lc & 7;
#pragma unroll
                for (int r = 0; r < 4; ++r) {
                    int m = quad * 4 + r;    // C/D layout: row=(l>>4)*4+r
                    float x = p0[r] + p1[r] + p2[r] + p3[r] + av[r];
                    float e2 = __expf(-2.f * fabsf(x));
                    float th = copysignf((1.f - e2) / (1.f + e2), x);
                    hstage[(q2 * 16 + m) * 8 + jj] = f2bf(th);
                    if (t == TT) out[(size_t)m * DD + c0 + lc] = th;
                }
                // Publish own half: wave w wrote exactly hstage u64s
                // w*64..w*64+63 (q2 in {2w,2w+1}); same-wave LDS round trip,
                // no barrier needed.
                asm volatile("s_waitcnt lgkmcnt(0)" ::: "memory");
                u64_t v = ((const u64_t*)hstage)[w * 64 + l];
                u64_t* dq = (u64_t*)(Hf + (size_t)t * HF_SLOT + (size_t)b * 512);
                llc_store64(dq + w * 64 + l, v);
                __builtin_amdgcn_s_waitcnt(0);   // own store acked at LLC
                if (l == 0)
                    __hip_atomic_store(&flags[b * FSTRIDE + w], (unsigned)t,
                                       __ATOMIC_RELAXED, __HIP_MEMORY_SCOPE_AGENT);
            } else {
#pragma unroll
                for (int r = 0; r < 4; ++r) {
                    int m = quad * 4 + r;
                    float y = p0[r] + p1[r] + p2[r] + p3[r];
                    ys[(size_t)((t - 1) * 16 + m) * DD + c0 + lc] = y;
                }
            }
        }
        // No trailing barrier: scr/hstage reuse at t+1 is protected by the
        // next iteration's poll barrier (hstage halves are wave-private).
    }
}

// ---------------------------------------------------------------------------
extern "C" void kernel_launch(void* const* d_in, const int* in_sizes, int n_in,
                              void* d_out, int out_size, void* d_ws, size_t ws_size,
                              hipStream_t stream) {
    const float* h0 = (const float*)d_in[0];
    const float* x  = (const float*)d_in[1];
    const float* Wx = (const float*)d_in[2];
    const float* Wh = (const float*)d_in[3];
    const float* Wo = (const float*)d_in[4];
    float* out = (float*)d_out;

    char* ws = (char*)d_ws;
    unsigned* flags = (unsigned*)ws;                             // 4 KB (64 lines, 64B stride)
    ushort_t* Hf  = (ushort_t*)(ws + 4096);                      // 513 slots * 64KB
    ushort_t* Xf  = Hf + HF_SLOT;                                // alias slots 1..512 (dead after phase 1)
    size_t hf_bytes = (size_t)(TT + 1) * HF_SLOT * 2;
    ushort_t* Wxt = (ushort_t*)(ws + 4096 + hf_bytes);
    ushort_t* Wht = Wxt + (size_t)DD * DD;
    ushort_t* Wot = Wht + (size_t)DD * DD;
    float* A32 = out + HF_SLOT;                                  // ys region; y writes trail A32 reads

    hipMemsetAsync(d_ws, 0, 4096, stream);

    // fp32 -> bf16 layout conversions
    conv_frag<<<8192, 256, 0, stream>>>(x, Xf);                  // X fragments
    conv_frag<<<16, 256, 0, stream>>>(h0, Hf);                   // h0 -> slot 0
    conv_wt<<<2048, 256, 0, stream>>>(Wx, Wxt);
    conv_wt<<<2048, 256, 0, stream>>>(Wh, Wht);
    conv_wt<<<2048, 256, 0, stream>>>(Wo, Wot);

    // Phase 1: A32 = X @ Wx   (fp32, lives in d_out's ys region)
    gemm_frag<<<dim3(64, 16), 256, 0, stream>>>(Xf, Wxt, A32);

    // Phase 2+3 fused: recurrence + streaming y = h @ Wo
    rnn_fused<<<2 * NBLK, 256, 0, stream>>>(Wht, Wot, Hf, A32, out, flags);
}